// Round 8
// baseline (160.136 us; speedup 1.0000x reference)
//
#include <hip/hip_runtime.h>

typedef _Float16 f16;
typedef f16   f16x4 __attribute__((ext_vector_type(4)));
typedef f16   f16x8 __attribute__((ext_vector_type(8)));
typedef float f32x4 __attribute__((ext_vector_type(4)));
typedef __attribute__((address_space(3))) char as3char;

#define MFMA16(a, b, c) __builtin_amdgcn_mfma_f32_16x16x32_f16((a), (b), (c), 0, 0, 0)

// ---- weight images in d_ws (f16 units). granule = [64n][64k] = 4096 f16 = 8KB ----
#define IMG_W1   0        // 8 granules (kq*2+nh)
#define IMG_W2   32768    // 2 granules (kh)
#define IMG_GW1  40960    // [32n][64k] = 2048
#define IMG_EW1  43008    // (e*2+mh)*4096
#define IMG_EW2  75776    // (e*2+kh)*4096
#define IMG_SW   108544   // 4096
#define IMG_HW1  112640   // 3 * 2048

__device__ __forceinline__ float silu_f(float v) {
    return v * __builtin_amdgcn_rcpf(1.0f + __expf(-v));
}

// ============ prep: fp32 src[K][N] block -> f16 granule [n][k ^ ((n&7)<<3)] ============
__device__ void conv_blk(const float* __restrict__ src, f16* __restrict__ dst,
                         int srcN, int k0, int n0, int KB, int NB, int tid, int nth) {
    for (int i = tid; i < KB * NB; i += nth) {
        const int kk = i / NB, nn = i - kk * NB;
        dst[nn * KB + (kk ^ ((nn & 7) << 3))] = (f16)src[(long)(k0 + kk) * srcN + n0 + nn];
    }
}

__global__ void prep_weights(const float* __restrict__ w1, const float* __restrict__ w2,
                             const float* __restrict__ gw1, const float* __restrict__ ew1,
                             const float* __restrict__ ew2, const float* __restrict__ sw,
                             const float* __restrict__ hw1, f16* __restrict__ ws) {
    const int tid = blockIdx.x * 256 + threadIdx.x;
    const int nth = gridDim.x * 256;
    for (int kq = 0; kq < 4; ++kq)
        for (int nh = 0; nh < 2; ++nh)
            conv_blk(w1, ws + IMG_W1 + (kq * 2 + nh) * 4096, 128, kq * 64, nh * 64, 64, 64, tid, nth);
    for (int kh = 0; kh < 2; ++kh)
        conv_blk(w2, ws + IMG_W2 + kh * 4096, 64, kh * 64, 0, 64, 64, tid, nth);
    conv_blk(gw1, ws + IMG_GW1, 32, 0, 0, 64, 32, tid, nth);
    for (int e = 0; e < 4; ++e)
        for (int h = 0; h < 2; ++h) {
            conv_blk(ew1 + e * 8192, ws + IMG_EW1 + (e * 2 + h) * 4096, 128, 0, h * 64, 64, 64, tid, nth);
            conv_blk(ew2 + e * 8192, ws + IMG_EW2 + (e * 2 + h) * 4096,  64, h * 64, 0, 64, 64, tid, nth);
        }
    conv_blk(sw, ws + IMG_SW, 64, 0, 0, 64, 64, tid, nth);
    for (int h = 0; h < 3; ++h)
        conv_blk(hw1 + h * 2048, ws + IMG_HW1 + h * 2048, 32, 0, 0, 64, 32, tid, nth);
}

// ============ async global->LDS staging: 1KB chunks round-robined over 4 waves ============
// LDS destination is an address_space(3) pointer derived ONCE from the __shared__
// symbol (provably non-null) -> no generic->as3 addrspacecast at call sites
// (works around the V_CMP_NE_U32 $src_shared_base isel bug).
template<int BYTES>
__device__ __forceinline__ void stage4(const f16* __restrict__ g, as3char* l, int wv, int lane) {
    constexpr int CH = BYTES / 1024;
    #pragma unroll
    for (int ch = 0; ch < CH; ++ch)
        if ((ch & 3) == wv)
            __builtin_amdgcn_global_load_lds(
                (const __attribute__((address_space(1))) void*)((const char*)g + ch * 1024 + lane * 16),
                (__attribute__((address_space(3))) void*)(l + ch * 1024), 16, 0, 0);
}

// ============ swizzles ============
__device__ __forceinline__ int swzW(int n) { return (n & 7) << 3; }
__device__ __forceinline__ int swzS(int r) { return (((((r >> 2) & 3) << 1) | (r & 1))) << 3; }

__device__ __forceinline__ f16x8 ldW(const f16* base, int row_base, int k0, int lane) {
    const int r = row_base + (lane & 15);
    const int k = k0 + ((lane >> 4) << 3);
    return *(const f16x8*)(base + r * 64 + (k ^ swzW(r)));
}
__device__ __forceinline__ f16x8 ldS(const f16* strip, int row_base, int k0, int lane) {
    const int r = row_base + (lane & 15);
    const int k = k0 + ((lane >> 4) << 3);
    return *(const f16x8*)(strip + r * 64 + (k ^ swzS(r)));
}
__device__ __forceinline__ void stS(f16* strip, int row_base, int col_base, f32x4 v, int lane) {
    const int cc = col_base + (lane & 15);
    #pragma unroll
    for (int g = 0; g < 4; ++g) {
        const int r = row_base + ((lane >> 4) << 2) + g;
        strip[r * 64 + (cc ^ swzS(r))] = (f16)v[g];
    }
}

// 16 MFMAs: acc[2][4] += A[2][2] @ granule
__device__ __forceinline__ void mm16(const f16x8 a[2][2], const f16* wb, f32x4 acc[2][4], int lane) {
    #pragma unroll
    for (int ks = 0; ks < 2; ++ks)
        #pragma unroll
        for (int n = 0; n < 4; ++n) {
            const f16x8 b = ldW(wb, n * 16, ks * 32, lane);
            acc[0][n] = MFMA16(a[0][ks], b, acc[0][n]);
            acc[1][n] = MFMA16(a[1][ks], b, acc[1][n]);
        }
}

// silu(acc) -> strip -> A-frags
__device__ __forceinline__ void silu_to_frags(f16* strip, const f32x4 in[2][4], f16x8 outf[2][2], int lane) {
    #pragma unroll
    for (int m = 0; m < 2; ++m)
        #pragma unroll
        for (int n = 0; n < 4; ++n) {
            f32x4 v;
            #pragma unroll
            for (int g = 0; g < 4; ++g) v[g] = silu_f(in[m][n][g]);
            stS(strip, m * 16, n * 16, v, lane);
        }
    #pragma unroll
    for (int m = 0; m < 2; ++m)
        #pragma unroll
        for (int ks = 0; ks < 2; ++ks)
            outf[m][ks] = ldS(strip, m * 16, ks * 32, lane);
}

__device__ __forceinline__ f32x4 reduce16(f32x4 v) {
    #pragma unroll
    for (int m = 1; m <= 8; m <<= 1) {
        f32x4 o;
        #pragma unroll
        for (int i = 0; i < 4; ++i) o[i] = __shfl_xor(v[i], m, 64);
        v += o;
    }
    return v;
}

__global__ __launch_bounds__(256, 3)
void fused_net_mfma(const float* __restrict__ x,   const f16* __restrict__ wsp,
                    const float* __restrict__ b1,  const float* __restrict__ lng,
                    const float* __restrict__ lnb, const float* __restrict__ b2,
                    const float* __restrict__ eb1, const float* __restrict__ eb2,
                    const float* __restrict__ gb1, const float* __restrict__ gw2,
                    const float* __restrict__ gb2, const float* __restrict__ sb,
                    const float* __restrict__ hb1, const float* __restrict__ hw2,
                    const float* __restrict__ hb2, float* __restrict__ out)
{
    // 37 KB: strips 16K | WB0 8K | WB1 8K | G 4K | GWT 1K
    __shared__ __align__(16) f16 lds[18944];
    as3char* const LB = (as3char*)lds;          // single provenance-preserving cast
    const int lane = threadIdx.x & 63;
    const int wv   = threadIdx.x >> 6;
    const int c    = lane & 15;
    const int q    = lane >> 4;
    f16* STRIP = lds + wv * 2048;               // per-wave [32][64]
    f16* const WB0 = lds + 8192;   as3char* const WB0_3 = LB + 16384;
    f16* const WB1 = lds + 12288;  as3char* const WB1_3 = LB + 24576;
    f16* const G   = lds + 16384;  as3char* const G_3   = LB + 32768;
    f16* const GWT = lds + 18432;               // [wv][e][row32] f16 gate weights

    const long blockRow = (long)blockIdx.x * 128;
    const float* xw = x + (blockRow + wv * 32) * 256;   // this wave's 32 rows

    // ---- prologue: x quarter 0 -> regs; w1 granule 0 -> WB0; gw1 -> G ----
    float4 xr[8];
    #pragma unroll
    for (int j = 0; j < 8; ++j) {
        const int fl = j * 64 + lane;
        xr[j] = *(const float4*)(xw + (fl >> 4) * 256 + (fl & 15) * 4);
    }
    stage4<8192>(wsp + IMG_W1, WB0_3, wv, lane);
    stage4<4096>(wsp + IMG_GW1, G_3, wv, lane);
    __syncthreads();

    // ================= stem1: acc = x @ w1 + b1 (8 granule phases) =================
    f32x4 acc[2][8];
    #pragma unroll
    for (int n8 = 0; n8 < 8; ++n8) {
        const float bv = b1[n8 * 16 + c];
        f32x4 t = {bv, bv, bv, bv};
        acc[0][n8] = t; acc[1][n8] = t;
    }

    #pragma unroll 1
    for (int kq = 0; kq < 4; ++kq) {
        // write x quarter to strip, read A-frags (reused for both nh phases)
        #pragma unroll
        for (int j = 0; j < 8; ++j) {
            const int fl = j * 64 + lane;
            const int row = fl >> 4, col = (fl & 15) * 4;
            f16x4 o; o[0] = (f16)xr[j].x; o[1] = (f16)xr[j].y; o[2] = (f16)xr[j].z; o[3] = (f16)xr[j].w;
            *(f16x4*)(STRIP + row * 64 + (col ^ swzS(row))) = o;
        }
        f16x8 af[2][2];
        #pragma unroll
        for (int m = 0; m < 2; ++m)
            #pragma unroll
            for (int ks = 0; ks < 2; ++ks)
                af[m][ks] = ldS(STRIP, m * 16, ks * 32, lane);

        // phase nh=0 (WB0): stage (kq,1) -> WB1
        stage4<8192>(wsp + IMG_W1 + (kq * 2 + 1) * 4096, WB1_3, wv, lane);
        {
            f32x4 a4[2][4] = {{acc[0][0],acc[0][1],acc[0][2],acc[0][3]},
                              {acc[1][0],acc[1][1],acc[1][2],acc[1][3]}};
            mm16(af, WB0, a4, lane);
            #pragma unroll
            for (int n = 0; n < 4; ++n) { acc[0][n] = a4[0][n]; acc[1][n] = a4[1][n]; }
        }
        __syncthreads();

        // phase nh=1 (WB1): prefetch x(kq+1); stage next (kq+1,0) or w2kh0 -> WB0
        if (kq < 3) {
            #pragma unroll
            for (int j = 0; j < 8; ++j) {
                const int fl = j * 64 + lane;
                xr[j] = *(const float4*)(xw + (fl >> 4) * 256 + (kq + 1) * 64 + (fl & 15) * 4);
            }
        }
        const f16* nsrc = (kq < 3) ? (wsp + IMG_W1 + (kq + 1) * 2 * 4096) : (wsp + IMG_W2);
        stage4<8192>(nsrc, WB0_3, wv, lane);
        {
            f32x4 a4[2][4] = {{acc[0][4],acc[0][5],acc[0][6],acc[0][7]},
                              {acc[1][4],acc[1][5],acc[1][6],acc[1][7]}};
            mm16(af, WB1, a4, lane);
            #pragma unroll
            for (int n = 0; n < 4; ++n) { acc[0][4 + n] = a4[0][n]; acc[1][4 + n] = a4[1][n]; }
        }
        __syncthreads();
    }

    // ---- LN stats (registers only) ----
    f32x4 mu[2], rs[2];
    #pragma unroll
    for (int m = 0; m < 2; ++m) {
        f32x4 s = {0,0,0,0}, qq = {0,0,0,0};
        #pragma unroll
        for (int n8 = 0; n8 < 8; ++n8) { s += acc[m][n8]; qq += acc[m][n8] * acc[m][n8]; }
        s = reduce16(s); qq = reduce16(qq);
        mu[m] = s * 0.0078125f;
        #pragma unroll
        for (int g = 0; g < 4; ++g)
            rs[m][g] = rsqrtf(qq[g] * 0.0078125f - mu[m][g] * mu[m][g] + 1e-5f);
    }

    // ================= stem2 (2 phases) + gate =================
    f32x4 a2[2][4];
    #pragma unroll
    for (int n = 0; n < 4; ++n) {
        const float bv = b2[n * 16 + c];
        f32x4 t = {bv, bv, bv, bv};
        a2[0][n] = t; a2[1][n] = t;
    }
    f16x8 hbA[2][2];

    #pragma unroll 1
    for (int kh = 0; kh < 2; ++kh) {
        // stage: kh=0 -> w2kh1 into WB1 ; kh=1 -> ew1[0]m0 into WB0
        if (kh == 0) stage4<8192>(wsp + IMG_W2 + 4096, WB1_3, wv, lane);
        else         stage4<8192>(wsp + IMG_EW1, WB0_3, wv, lane);
        // LN half kh -> strip
        #pragma unroll
        for (int m = 0; m < 2; ++m)
            #pragma unroll
            for (int n = 0; n < 4; ++n) {
                const int j = kh * 64 + n * 16 + c;
                const float gg = lng[j], bb = lnb[j];
                f32x4 v;
                #pragma unroll
                for (int g = 0; g < 4; ++g)
                    v[g] = silu_f((acc[m][kh * 4 + n][g] - mu[m][g]) * rs[m][g] * gg + bb);
                stS(STRIP, m * 16, n * 16, v, lane);
            }
        f16x8 af[2][2];
        #pragma unroll
        for (int m = 0; m < 2; ++m)
            #pragma unroll
            for (int ks = 0; ks < 2; ++ks)
                af[m][ks] = ldS(STRIP, m * 16, ks * 32, lane);
        mm16(af, kh == 0 ? WB0 : WB1, a2, lane);
        if (kh == 1) {
            // hb = silu(a2) -> strip -> A-frags (kept in regs through all experts)
            silu_to_frags(STRIP, a2, hbA, lane);
            // gate: logits -> softmax -> GWT (per-wave LDS)
            f32x4 ag[2][2];
            #pragma unroll
            for (int n = 0; n < 2; ++n) {
                const float bv = gb1[n * 16 + c];
                f32x4 t = {bv, bv, bv, bv};
                ag[0][n] = t; ag[1][n] = t;
            }
            #pragma unroll
            for (int ks = 0; ks < 2; ++ks)
                #pragma unroll
                for (int n = 0; n < 2; ++n) {
                    const f16x8 b = ldW(G, n * 16, ks * 32, lane);
                    ag[0][n] = MFMA16(hbA[0][ks], b, ag[0][n]);
                    ag[1][n] = MFMA16(hbA[1][ks], b, ag[1][n]);
                }
            const f32x4 gb2v = *(const f32x4*)gb2;
            #pragma unroll
            for (int m = 0; m < 2; ++m) {
                f32x4 pg[4] = {{0,0,0,0},{0,0,0,0},{0,0,0,0},{0,0,0,0}};
                #pragma unroll
                for (int n = 0; n < 2; ++n) {
                    const f32x4 w4 = *(const f32x4*)(gw2 + (n * 16 + c) * 4);
                    #pragma unroll
                    for (int g = 0; g < 4; ++g)
                        pg[g] += silu_f(ag[m][n][g]) * w4;
                }
                #pragma unroll
                for (int g = 0; g < 4; ++g) {
                    f32x4 l = reduce16(pg[g]) + gb2v;
                    const float mx = fmaxf(fmaxf(l[0], l[1]), fmaxf(l[2], l[3]));
                    f32x4 ee;
                    #pragma unroll
                    for (int o = 0; o < 4; ++o) ee[o] = __expf(l[o] - mx);
                    const f32x4 gv = ee * __builtin_amdgcn_rcpf(ee[0] + ee[1] + ee[2] + ee[3]);
                    if (c < 4) {
                        const float val = (c == 0) ? gv[0] : (c == 1) ? gv[1] : (c == 2) ? gv[2] : gv[3];
                        GWT[wv * 128 + c * 32 + m * 16 + q * 4 + g] = (f16)val;
                    }
                }
            }
        }
        __syncthreads();
    }

    // ================= 4 experts (rolled, 4 phases each) =================
    f32x4 moe[2][4] = {{{0,0,0,0},{0,0,0,0},{0,0,0,0},{0,0,0,0}},
                       {{0,0,0,0},{0,0,0,0},{0,0,0,0},{0,0,0,0}}};
    #pragma unroll 1
    for (int e = 0; e < 4; ++e) {
        f16x8 ea[2][2];
        f32x4 a2e[2][4];
        #pragma unroll
        for (int n = 0; n < 4; ++n) {
            const float bv = eb2[e * 64 + n * 16 + c];
            f32x4 t = {bv, bv, bv, bv};
            a2e[0][n] = t; a2e[1][n] = t;
        }
        // phase A (WB0 = ew1 m0): stage ew2 k0 -> WB1
        stage4<8192>(wsp + IMG_EW2 + (e * 2) * 4096, WB1_3, wv, lane);
        {
            f32x4 aa[2][4];
            #pragma unroll
            for (int n = 0; n < 4; ++n) {
                const float bv = eb1[e * 128 + n * 16 + c];
                f32x4 t = {bv, bv, bv, bv};
                aa[0][n] = t; aa[1][n] = t;
            }
            mm16(hbA, WB0, aa, lane);
            silu_to_frags(STRIP, aa, ea, lane);
        }
        __syncthreads();
        // phase B (WB1 = ew2 k0): stage ew1 m1 -> WB0
        stage4<8192>(wsp + IMG_EW1 + (e * 2 + 1) * 4096, WB0_3, wv, lane);
        mm16(ea, WB1, a2e, lane);
        __syncthreads();
        // phase C (WB0 = ew1 m1): stage ew2 k1 -> WB1
        stage4<8192>(wsp + IMG_EW2 + (e * 2 + 1) * 4096, WB1_3, wv, lane);
        {
            f32x4 aa[2][4];
            #pragma unroll
            for (int n = 0; n < 4; ++n) {
                const float bv = eb1[e * 128 + 64 + n * 16 + c];
                f32x4 t = {bv, bv, bv, bv};
                aa[0][n] = t; aa[1][n] = t;
            }
            mm16(hbA, WB0, aa, lane);
            silu_to_frags(STRIP, aa, ea, lane);
        }
        __syncthreads();
        // phase D (WB1 = ew2 k1): stage next ew1 m0 (or sw) -> WB0
        stage4<8192>((e < 3) ? (wsp + IMG_EW1 + (e + 1) * 2 * 4096) : (wsp + IMG_SW), WB0_3, wv, lane);
        mm16(ea, WB1, a2e, lane);
        #pragma unroll
        for (int m = 0; m < 2; ++m)
            #pragma unroll
            for (int g = 0; g < 4; ++g) {
                const float ge = (float)GWT[wv * 128 + e * 32 + m * 16 + q * 4 + g];
                #pragma unroll
                for (int n = 0; n < 4; ++n)
                    moe[m][n][g] += silu_f(a2e[m][n][g]) * ge;
            }
        __syncthreads();
    }

    // ================= shared trunk (WB0 = sw): stage hw1[0,1]->WB1, hw1[2]->G =================
    stage4<8192>(wsp + IMG_HW1, WB1_3, wv, lane);
    stage4<4096>(wsp + IMG_HW1 + 4096, G_3, wv, lane);
    f16x8 featA[2][2];
    {
        #pragma unroll
        for (int m = 0; m < 2; ++m)
            #pragma unroll
            for (int n = 0; n < 4; ++n)
                stS(STRIP, m * 16, n * 16, moe[m][n], lane);
        f16x8 ma[2][2];
        #pragma unroll
        for (int m = 0; m < 2; ++m)
            #pragma unroll
            for (int ks = 0; ks < 2; ++ks)
                ma[m][ks] = ldS(STRIP, m * 16, ks * 32, lane);
        f32x4 fs[2][4];
        #pragma unroll
        for (int n = 0; n < 4; ++n) {
            const float bv = sb[n * 16 + c];
            f32x4 t = {bv, bv, bv, bv};
            fs[0][n] = t; fs[1][n] = t;
        }
        mm16(ma, WB0, fs, lane);
        silu_to_frags(STRIP, fs, featA, lane);
    }
    __syncthreads();

    // ================= heads (WB1 = hw1[0,1], G = hw1[2]) =================
    {
        f32x4 ah[2][6];
        #pragma unroll
        for (int n = 0; n < 6; ++n) {
            const float bv = hb1[(n >> 1) * 32 + (n & 1) * 16 + c];
            f32x4 t = {bv, bv, bv, bv};
            ah[0][n] = t; ah[1][n] = t;
        }
        #pragma unroll
        for (int ks = 0; ks < 2; ++ks)
            #pragma unroll
            for (int n = 0; n < 6; ++n) {
                const int h = n >> 1;
                const f16* hw = (h < 2) ? (WB1 + h * 2048) : G;
                const f16x8 b = ldW(hw, (n & 1) * 16, ks * 32, lane);
                ah[0][n] = MFMA16(featA[0][ks], b, ah[0][n]);
                ah[1][n] = MFMA16(featA[1][ks], b, ah[1][n]);
            }
        const float hb2_0 = hb2[0], hb2_1 = hb2[1], hb2_2 = hb2[2];
        #pragma unroll
        for (int m = 0; m < 2; ++m) {
            f32x4 ph[3] = {{0,0,0,0},{0,0,0,0},{0,0,0,0}};
            #pragma unroll
            for (int n = 0; n < 6; ++n) {
                const int h = n >> 1;
                const float w2v = hw2[h * 32 + (n & 1) * 16 + c];
                #pragma unroll
                for (int g = 0; g < 4; ++g)
                    ph[h][g] += silu_f(ah[m][n][g]) * w2v;
            }
            #pragma unroll
            for (int h = 0; h < 3; ++h) ph[h] = reduce16(ph[h]);
            #pragma unroll
            for (int g = 0; g < 4; ++g) {
                const long row = blockRow + wv * 32 + m * 16 + q * 4 + g;
                if (c < 3) {
                    const float r0 = ph[0][g] + hb2_0;
                    const float r1 = ph[1][g] + hb2_1;
                    const float r2 = ph[2][g] + hb2_2;
                    out[row * 3 + c] = (c == 0) ? r0 : ((c == 1) ? r1 : r2);
                }
            }
        }
    }
}

extern "C" void kernel_launch(void* const* d_in, const int* in_sizes, int n_in,
                              void* d_out, int out_size, void* d_ws, size_t ws_size,
                              hipStream_t stream) {
    const float* x    = (const float*)d_in[0];
    const float* w1   = (const float*)d_in[1];
    const float* b1   = (const float*)d_in[2];
    const float* lng  = (const float*)d_in[3];
    const float* lnb  = (const float*)d_in[4];
    const float* w2   = (const float*)d_in[5];
    const float* b2   = (const float*)d_in[6];
    const float* ew1  = (const float*)d_in[7];
    const float* eb1  = (const float*)d_in[8];
    const float* ew2  = (const float*)d_in[9];
    const float* eb2  = (const float*)d_in[10];
    const float* gw1  = (const float*)d_in[11];
    const float* gb1  = (const float*)d_in[12];
    const float* gw2  = (const float*)d_in[13];
    const float* gb2  = (const float*)d_in[14];
    const float* sw   = (const float*)d_in[15];
    const float* sb   = (const float*)d_in[16];
    const float* hw1  = (const float*)d_in[17];
    const float* hb1  = (const float*)d_in[18];
    const float* hw2  = (const float*)d_in[19];
    const float* hb2  = (const float*)d_in[20];
    float* out = (float*)d_out;
    f16* ws = (f16*)d_ws;

    hipLaunchKernelGGL(prep_weights, dim3(64), dim3(256), 0, stream,
                       w1, w2, gw1, ew1, ew2, sw, hw1, ws);

    const int B = in_sizes[0] / 256;
    const int grid = B / 128;
    hipLaunchKernelGGL(fused_net_mfma, dim3(grid), dim3(256), 0, stream,
                       x, ws, b1, lng, lnb, b2, eb1, eb2, gb1, gw2, gb2,
                       sb, hb1, hw2, hb2, out);
}

// Round 9
// 104.177 us; speedup vs baseline: 1.5371x; 1.5371x over previous
//
#include <hip/hip_runtime.h>

typedef _Float16 f16;
typedef f16   f16x4 __attribute__((ext_vector_type(4)));
typedef f16   f16x8 __attribute__((ext_vector_type(8)));
typedef float f32x4 __attribute__((ext_vector_type(4)));
typedef __attribute__((address_space(3))) char as3char;

#define MFMA16(a, b, c) __builtin_amdgcn_mfma_f32_16x16x32_f16((a), (b), (c), 0, 0, 0)

// ---- weight images in d_ws (f16 units). granule = [64n][64k] = 4096 f16 = 8KB ----
// refill unit = 8192 f16 = 16KB (one WB pair)
#define IMG_W1   0        // 4 pairs: pair kq = {granule(kq,n0..63), granule(kq,n64..127)}
#define IMG_W2   32768    // 1 pair: {w2 kh0, w2 kh1}
#define IMG_GW1  40960    // [32n][64k] = 2048
#define IMG_E    43008    // per e (16384): half h at +h*8192 = {ew1[e] colhalf h, ew2[e] rowhalf h}
#define IMG_SWH  108544   // pair: {sw (4096), hw1[0] (2048), hw1[1] (2048)}
#define IMG_HW2G 116736   // hw1[2] (2048)

__device__ __forceinline__ float silu_f(float v) {
    return v * __builtin_amdgcn_rcpf(1.0f + __expf(-v));
}

// ============ prep: fp32 src[K][N] block -> f16 granule [n][k ^ ((n&7)<<3)] ============
__device__ void conv_blk(const float* __restrict__ src, f16* __restrict__ dst,
                         int srcN, int k0, int n0, int KB, int NB, int tid, int nth) {
    for (int i = tid; i < KB * NB; i += nth) {
        const int kk = i / NB, nn = i - kk * NB;
        dst[nn * KB + (kk ^ ((nn & 7) << 3))] = (f16)src[(long)(k0 + kk) * srcN + n0 + nn];
    }
}

__global__ void prep_weights(const float* __restrict__ w1, const float* __restrict__ w2,
                             const float* __restrict__ gw1, const float* __restrict__ ew1,
                             const float* __restrict__ ew2, const float* __restrict__ sw,
                             const float* __restrict__ hw1, f16* __restrict__ ws) {
    const int tid = blockIdx.x * 256 + threadIdx.x;
    const int nth = gridDim.x * 256;
    for (int kq = 0; kq < 4; ++kq)
        for (int nh = 0; nh < 2; ++nh)
            conv_blk(w1, ws + IMG_W1 + (kq * 2 + nh) * 4096, 128, kq * 64, nh * 64, 64, 64, tid, nth);
    for (int kh = 0; kh < 2; ++kh)
        conv_blk(w2, ws + IMG_W2 + kh * 4096, 64, kh * 64, 0, 64, 64, tid, nth);
    conv_blk(gw1, ws + IMG_GW1, 32, 0, 0, 64, 32, tid, nth);
    for (int e = 0; e < 4; ++e)
        for (int h = 0; h < 2; ++h) {
            conv_blk(ew1 + e * 8192, ws + IMG_E + e * 16384 + h * 8192,        128, 0, h * 64, 64, 64, tid, nth);
            conv_blk(ew2 + e * 8192, ws + IMG_E + e * 16384 + h * 8192 + 4096,  64, h * 64, 0, 64, 64, tid, nth);
        }
    conv_blk(sw, ws + IMG_SWH, 64, 0, 0, 64, 64, tid, nth);
    for (int h = 0; h < 2; ++h)
        conv_blk(hw1 + h * 2048, ws + IMG_SWH + 4096 + h * 2048, 32, 0, 0, 64, 32, tid, nth);
    conv_blk(hw1 + 2 * 2048, ws + IMG_HW2G, 32, 0, 0, 64, 32, tid, nth);
}

// ============ async global->LDS staging: 1KB chunks round-robined over 4 waves ============
template<int BYTES>
__device__ __forceinline__ void stage4(const f16* __restrict__ g, as3char* l, int wv, int lane) {
    constexpr int CH = BYTES / 1024;
    #pragma unroll
    for (int ch = 0; ch < CH; ++ch)
        if ((ch & 3) == wv)
            __builtin_amdgcn_global_load_lds(
                (const __attribute__((address_space(1))) void*)((const char*)g + ch * 1024 + lane * 16),
                (__attribute__((address_space(3))) void*)(l + ch * 1024), 16, 0, 0);
}

// ============ swizzles ============
__device__ __forceinline__ int swzW(int n) { return (n & 7) << 3; }
__device__ __forceinline__ int swzS(int r) { return (((((r >> 2) & 3) << 1) | (r & 1))) << 3; }

__device__ __forceinline__ f16x8 ldW(const f16* base, int row_base, int k0, int lane) {
    const int r = row_base + (lane & 15);
    const int k = k0 + ((lane >> 4) << 3);
    return *(const f16x8*)(base + r * 64 + (k ^ swzW(r)));
}
__device__ __forceinline__ f16x8 ldS(const f16* strip, int k0, int lane) {
    const int r = lane & 15;
    const int k = k0 + ((lane >> 4) << 3);
    return *(const f16x8*)(strip + r * 64 + (k ^ swzS(r)));
}
__device__ __forceinline__ void stS(f16* strip, int col_base, f32x4 v, int lane) {
    const int cc = col_base + (lane & 15);
    #pragma unroll
    for (int g = 0; g < 4; ++g) {
        const int r = ((lane >> 4) << 2) + g;
        strip[r * 64 + (cc ^ swzS(r))] = (f16)v[g];
    }
}

// 8 MFMAs: acc[4] += A[2] @ granule (M=16 rows)
__device__ __forceinline__ void mm8(const f16x8 a[2], const f16* wb, f32x4 acc[4], int lane) {
    #pragma unroll
    for (int ks = 0; ks < 2; ++ks)
        #pragma unroll
        for (int n = 0; n < 4; ++n) {
            const f16x8 b = ldW(wb, n * 16, ks * 32, lane);
            acc[n] = MFMA16(a[ks], b, acc[n]);
        }
}

// silu(acc) -> strip -> A-frags
__device__ __forceinline__ void silu_to_frags(f16* strip, const f32x4 in[4], f16x8 outf[2], int lane) {
    #pragma unroll
    for (int n = 0; n < 4; ++n) {
        f32x4 v;
        #pragma unroll
        for (int g = 0; g < 4; ++g) v[g] = silu_f(in[n][g]);
        stS(strip, n * 16, v, lane);
    }
    #pragma unroll
    for (int ks = 0; ks < 2; ++ks)
        outf[ks] = ldS(strip, ks * 32, lane);
}

__device__ __forceinline__ f32x4 reduce16(f32x4 v) {
    #pragma unroll
    for (int m = 1; m <= 8; m <<= 1) {
        f32x4 o;
        #pragma unroll
        for (int i = 0; i < 4; ++i) o[i] = __shfl_xor(v[i], m, 64);
        v += o;
    }
    return v;
}

__global__ __launch_bounds__(256, 5)
void fused_net_mfma(const float* __restrict__ x,   const f16* __restrict__ wsp,
                    const float* __restrict__ b1,  const float* __restrict__ lng,
                    const float* __restrict__ lnb, const float* __restrict__ b2,
                    const float* __restrict__ eb1, const float* __restrict__ eb2,
                    const float* __restrict__ gb1, const float* __restrict__ gw2,
                    const float* __restrict__ gb2, const float* __restrict__ sb,
                    const float* __restrict__ hb1, const float* __restrict__ hw2,
                    const float* __restrict__ hb2, float* __restrict__ out)
{
    // 29184 B: strips 4x2KB | WB pair 16KB | G 4KB | GWT 0.5KB  -> 5 blocks/CU
    __shared__ __align__(16) f16 lds[14592];
    as3char* const LB = (as3char*)lds;          // single provenance-preserving cast
    const int lane = threadIdx.x & 63;
    const int wv   = threadIdx.x >> 6;
    const int c    = lane & 15;
    const int q    = lane >> 4;
    f16* STRIP = lds + wv * 1024;               // per-wave [16][64]
    f16* const WB0 = lds + 4096;   as3char* const WB_3 = LB + 8192;   // pair dest
    f16* const WB1 = lds + 8192;
    f16* const G   = lds + 12288;  as3char* const G_3  = LB + 24576;
    f16* const GWT = lds + 14336;               // [wv][e][16 rows] f16

    const long blockRow = (long)blockIdx.x * 64;
    const float* xw = x + (blockRow + wv * 16) * 256;   // this wave's 16 rows

    // ---- prologue: w1 pair0 -> WB, gw1 -> G ----
    stage4<16384>(wsp + IMG_W1, WB_3, wv, lane);
    stage4<4096>(wsp + IMG_GW1, G_3, wv, lane);
    __syncthreads();

    // ================= stem1: acc = x @ w1 + b1 (4 pair phases) =================
    f32x4 acc[8];
    #pragma unroll
    for (int n8 = 0; n8 < 8; ++n8) {
        const float bv = b1[n8 * 16 + c];
        f32x4 t = {bv, bv, bv, bv};
        acc[n8] = t;
    }

    #pragma unroll 1
    for (int kq = 0; kq < 4; ++kq) {
        // x quarter kq -> strip (coalesced float4, transient regs)
        #pragma unroll
        for (int i = 0; i < 4; ++i) {
            const int idx4 = lane + i * 64;
            const int r  = idx4 >> 4;
            const int c4 = (idx4 & 15) << 2;
            const float4 v = *(const float4*)(xw + r * 256 + kq * 64 + c4);
            f16x4 o; o[0] = (f16)v.x; o[1] = (f16)v.y; o[2] = (f16)v.z; o[3] = (f16)v.w;
            *(f16x4*)(STRIP + r * 64 + (c4 ^ swzS(r))) = o;
        }
        f16x8 af[2];
        #pragma unroll
        for (int ks = 0; ks < 2; ++ks)
            af[ks] = ldS(STRIP, ks * 32, lane);

        mm8(af, WB0, acc,     lane);   // N 0..63
        mm8(af, WB1, acc + 4, lane);   // N 64..127
        __syncthreads();               // pair reads done
        const f16* nsrc = (kq < 3) ? (wsp + IMG_W1 + (kq + 1) * 8192) : (wsp + IMG_W2);
        stage4<16384>(nsrc, WB_3, wv, lane);
        __syncthreads();               // next pair ready
    }

    // ---- LN stats (registers only) ----
    f32x4 mu, rs;
    {
        f32x4 s = {0,0,0,0}, qq = {0,0,0,0};
        #pragma unroll
        for (int n8 = 0; n8 < 8; ++n8) { s += acc[n8]; qq += acc[n8] * acc[n8]; }
        s = reduce16(s); qq = reduce16(qq);
        mu = s * 0.0078125f;
        #pragma unroll
        for (int g = 0; g < 4; ++g)
            rs[g] = rsqrtf(qq[g] * 0.0078125f - mu[g] * mu[g] + 1e-5f);
    }

    // ================= stem2 (WB = w2 pair) =================
    f32x4 a2[4];
    #pragma unroll
    for (int n = 0; n < 4; ++n) {
        const float bv = b2[n * 16 + c];
        f32x4 t = {bv, bv, bv, bv};
        a2[n] = t;
    }
    #pragma unroll
    for (int kh = 0; kh < 2; ++kh) {
        #pragma unroll
        for (int n = 0; n < 4; ++n) {
            const int j = kh * 64 + n * 16 + c;
            const float gg = lng[j], bb = lnb[j];
            f32x4 v;
            #pragma unroll
            for (int g = 0; g < 4; ++g)
                v[g] = silu_f((acc[kh * 4 + n][g] - mu[g]) * rs[g] * gg + bb);
            stS(STRIP, n * 16, v, lane);
        }
        f16x8 af[2];
        #pragma unroll
        for (int ks = 0; ks < 2; ++ks)
            af[ks] = ldS(STRIP, ks * 32, lane);
        mm8(af, kh == 0 ? WB0 : WB1, a2, lane);
    }
    // hb = silu(a2) -> strip -> A-frags (8 VGPRs, held through experts)
    f16x8 hbA[2];
    silu_to_frags(STRIP, a2, hbA, lane);

    // ---- gate -> GWT (per-wave LDS; no barrier needed for own reads) ----
    {
        f32x4 ag[2];
        #pragma unroll
        for (int n = 0; n < 2; ++n) {
            const float bv = gb1[n * 16 + c];
            f32x4 t = {bv, bv, bv, bv};
            ag[n] = t;
        }
        #pragma unroll
        for (int ks = 0; ks < 2; ++ks)
            #pragma unroll
            for (int n = 0; n < 2; ++n) {
                const f16x8 b = ldW(G, n * 16, ks * 32, lane);
                ag[n] = MFMA16(hbA[ks], b, ag[n]);
            }
        const f32x4 gb2v = *(const f32x4*)gb2;
        f32x4 pg[4] = {{0,0,0,0},{0,0,0,0},{0,0,0,0},{0,0,0,0}};
        #pragma unroll
        for (int n = 0; n < 2; ++n) {
            const f32x4 w4 = *(const f32x4*)(gw2 + (n * 16 + c) * 4);
            #pragma unroll
            for (int g = 0; g < 4; ++g)
                pg[g] += silu_f(ag[n][g]) * w4;
        }
        #pragma unroll
        for (int g = 0; g < 4; ++g) {
            f32x4 l = reduce16(pg[g]) + gb2v;
            const float mx = fmaxf(fmaxf(l[0], l[1]), fmaxf(l[2], l[3]));
            f32x4 ee;
            #pragma unroll
            for (int o = 0; o < 4; ++o) ee[o] = __expf(l[o] - mx);
            const f32x4 gv = ee * __builtin_amdgcn_rcpf(ee[0] + ee[1] + ee[2] + ee[3]);
            if (c < 4) {
                const float val = (c == 0) ? gv[0] : (c == 1) ? gv[1] : (c == 2) ? gv[2] : gv[3];
                GWT[wv * 64 + c * 16 + q * 4 + g] = (f16)val;
            }
        }
    }

    // ================= 4 experts (rolled; 2 refills each) =================
    f32x4 moe[4] = {{0,0,0,0},{0,0,0,0},{0,0,0,0},{0,0,0,0}};
    #pragma unroll 1
    for (int e = 0; e < 4; ++e) {
        f32x4 a2e[4];
        #pragma unroll
        for (int n = 0; n < 4; ++n) {
            const float bv = eb2[e * 64 + n * 16 + c];
            f32x4 t = {bv, bv, bv, bv};
            a2e[n] = t;
        }
        #pragma unroll
        for (int h = 0; h < 2; ++h) {
            __syncthreads();   // prior WB reads done
            stage4<16384>(wsp + IMG_E + e * 16384 + h * 8192, WB_3, wv, lane);
            __syncthreads();   // WB0 = ew1[e] colhalf h, WB1 = ew2[e] rowhalf h
            f32x4 aa[4];
            #pragma unroll
            for (int n = 0; n < 4; ++n) {
                const float bv = eb1[e * 128 + h * 64 + n * 16 + c];
                f32x4 t = {bv, bv, bv, bv};
                aa[n] = t;
            }
            mm8(hbA, WB0, aa, lane);
            f16x8 ea[2];
            silu_to_frags(STRIP, aa, ea, lane);
            mm8(ea, WB1, a2e, lane);
        }
        #pragma unroll
        for (int g = 0; g < 4; ++g) {
            const float ge = (float)GWT[wv * 64 + e * 16 + q * 4 + g];
            #pragma unroll
            for (int n = 0; n < 4; ++n)
                moe[n][g] += silu_f(a2e[n][g]) * ge;
        }
    }

    // ================= final refill: {sw, hw1[0], hw1[1]} -> WB, hw1[2] -> G =================
    __syncthreads();
    stage4<16384>(wsp + IMG_SWH, WB_3, wv, lane);
    stage4<4096>(wsp + IMG_HW2G, G_3, wv, lane);
    __syncthreads();

    // shared trunk: feat = silu(moe @ sw + sb)
    f16x8 featA[2];
    {
        #pragma unroll
        for (int n = 0; n < 4; ++n)
            stS(STRIP, n * 16, moe[n], lane);
        f16x8 ma[2];
        #pragma unroll
        for (int ks = 0; ks < 2; ++ks)
            ma[ks] = ldS(STRIP, ks * 32, lane);
        f32x4 fs[4];
        #pragma unroll
        for (int n = 0; n < 4; ++n) {
            const float bv = sb[n * 16 + c];
            f32x4 t = {bv, bv, bv, bv};
            fs[n] = t;
        }
        mm8(ma, WB0, fs, lane);
        silu_to_frags(STRIP, fs, featA, lane);
    }

    // heads: WB1 = hw1[0] | hw1[1], G = hw1[2]
    {
        f32x4 ah[6];
        #pragma unroll
        for (int n = 0; n < 6; ++n) {
            const float bv = hb1[(n >> 1) * 32 + (n & 1) * 16 + c];
            f32x4 t = {bv, bv, bv, bv};
            ah[n] = t;
        }
        #pragma unroll
        for (int ks = 0; ks < 2; ++ks)
            #pragma unroll
            for (int n = 0; n < 6; ++n) {
                const int h = n >> 1;
                const f16* hw = (h == 0) ? WB1 : (h == 1) ? (WB1 + 2048) : G;
                const f16x8 b = ldW(hw, (n & 1) * 16, ks * 32, lane);
                ah[n] = MFMA16(featA[ks], b, ah[n]);
            }
        const float hb2_0 = hb2[0], hb2_1 = hb2[1], hb2_2 = hb2[2];
        f32x4 ph[3] = {{0,0,0,0},{0,0,0,0},{0,0,0,0}};
        #pragma unroll
        for (int n = 0; n < 6; ++n) {
            const int h = n >> 1;
            const float w2v = hw2[h * 32 + (n & 1) * 16 + c];
            #pragma unroll
            for (int g = 0; g < 4; ++g)
                ph[h][g] += silu_f(ah[n][g]) * w2v;
        }
        #pragma unroll
        for (int h = 0; h < 3; ++h) ph[h] = reduce16(ph[h]);
        #pragma unroll
        for (int g = 0; g < 4; ++g) {
            const long row = blockRow + wv * 16 + q * 4 + g;
            if (c < 3) {
                const float r0 = ph[0][g] + hb2_0;
                const float r1 = ph[1][g] + hb2_1;
                const float r2 = ph[2][g] + hb2_2;
                out[row * 3 + c] = (c == 0) ? r0 : ((c == 1) ? r1 : r2);
            }
        }
    }
}

extern "C" void kernel_launch(void* const* d_in, const int* in_sizes, int n_in,
                              void* d_out, int out_size, void* d_ws, size_t ws_size,
                              hipStream_t stream) {
    const float* x    = (const float*)d_in[0];
    const float* w1   = (const float*)d_in[1];
    const float* b1   = (const float*)d_in[2];
    const float* lng  = (const float*)d_in[3];
    const float* lnb  = (const float*)d_in[4];
    const float* w2   = (const float*)d_in[5];
    const float* b2   = (const float*)d_in[6];
    const float* ew1  = (const float*)d_in[7];
    const float* eb1  = (const float*)d_in[8];
    const float* ew2  = (const float*)d_in[9];
    const float* eb2  = (const float*)d_in[10];
    const float* gw1  = (const float*)d_in[11];
    const float* gb1  = (const float*)d_in[12];
    const float* gw2  = (const float*)d_in[13];
    const float* gb2  = (const float*)d_in[14];
    const float* sw   = (const float*)d_in[15];
    const float* sb   = (const float*)d_in[16];
    const float* hw1  = (const float*)d_in[17];
    const float* hb1  = (const float*)d_in[18];
    const float* hw2  = (const float*)d_in[19];
    const float* hb2  = (const float*)d_in[20];
    float* out = (float*)d_out;
    f16* ws = (f16*)d_ws;

    hipLaunchKernelGGL(prep_weights, dim3(64), dim3(256), 0, stream,
                       w1, w2, gw1, ew1, ew2, sw, hw1, ws);

    const int B = in_sizes[0] / 256;
    const int grid = B / 64;
    hipLaunchKernelGGL(fused_net_mfma, dim3(grid), dim3(256), 0, stream,
                       x, ws, b1, lng, lnb, b2, eb1, eb2, gb1, gw2, gb2,
                       sb, hb1, hw2, hb2, out);
}